// Round 1
// baseline (11.376 us; speedup 1.0000x reference)
//
#include <hip/hip_runtime.h>

// TripletLoss: N=16384 rows, M=4096 cols.
// loss_r = max( (s1>=s2 ? d1-d2 : d2-d1) + 100, 0 ),  out = sum_r loss_r / N
// Latency-bound random gather; one thread per row, deterministic 2-stage reduce.

#define N_ROWS 16384
#define M_COLS 4096
#define MARGIN 100.0f
#define NBLOCKS 64
#define NTHREADS 256

__global__ __launch_bounds__(NTHREADS) void triplet_partial(
    const float* __restrict__ D,
    const float* __restrict__ S,
    const int*   __restrict__ P,
    float* __restrict__ partial)
{
    const int r = blockIdx.x * NTHREADS + threadIdx.x;   // exactly N_ROWS threads

    // permutations is (N,3) int32; we need columns 1 and 2
    const int i1 = P[3 * r + 1];
    const int i2 = P[3 * r + 2];

    const float* Drow = D + (size_t)r * M_COLS;
    const float* Srow = S + (size_t)r * M_COLS;

    const float d1 = Drow[i1];
    const float d2 = Drow[i2];
    const float s1 = Srow[i1];
    const float s2 = Srow[i2];

    const float diff = (s1 >= s2) ? (d1 - d2) : (d2 - d1);
    float loss = fmaxf(diff + MARGIN, 0.0f);

    // wave (64-lane) reduction
    #pragma unroll
    for (int off = 32; off > 0; off >>= 1)
        loss += __shfl_down(loss, off);

    __shared__ float wsum[NTHREADS / 64];
    const int lane = threadIdx.x & 63;
    const int wid  = threadIdx.x >> 6;
    if (lane == 0) wsum[wid] = loss;
    __syncthreads();

    if (threadIdx.x == 0) {
        float s = 0.0f;
        #pragma unroll
        for (int w = 0; w < NTHREADS / 64; ++w) s += wsum[w];
        partial[blockIdx.x] = s;
    }
}

__global__ __launch_bounds__(64) void triplet_final(
    const float* __restrict__ partial,
    float* __restrict__ out)
{
    // NBLOCKS == 64 partials, one per lane
    float v = partial[threadIdx.x];
    #pragma unroll
    for (int off = 32; off > 0; off >>= 1)
        v += __shfl_down(v, off);
    if (threadIdx.x == 0)
        out[0] = v * (1.0f / (float)N_ROWS);
}

extern "C" void kernel_launch(void* const* d_in, const int* in_sizes, int n_in,
                              void* d_out, int out_size, void* d_ws, size_t ws_size,
                              hipStream_t stream)
{
    const float* D = (const float*)d_in[0];   // distances   (N, M) f32
    const float* S = (const float*)d_in[1];   // similarities(N, M) f32
    const int*   P = (const int*)  d_in[2];   // permutations(N, 3) int32
    float* out     = (float*)d_out;
    float* partial = (float*)d_ws;            // NBLOCKS floats of scratch

    triplet_partial<<<NBLOCKS, NTHREADS, 0, stream>>>(D, S, P, partial);
    triplet_final<<<1, 64, 0, stream>>>(partial, out);
}